// Round 10
// baseline (297.587 us; speedup 1.0000x reference)
//
#include <hip/hip_runtime.h>

// Problem: B=256, N=1000, D=128, H=8, dk=16. grid=256 (one block per b).
//
// R10: phase C staging via __builtin_amdgcn_global_load_lds (16B) into a
// DOUBLE-BUFFERED Et (2 x 64 KB), wave-local, zero barriers, fine-grained
// s_waitcnt vmcnt(4) — tile k+1's DMA stays in flight across tile k's
// compute (cp.async-style pipeline; cdna_hip_programming §5).
// Constraints honored: DMA needs lane-contiguous LDS (wave-uniform base +
// lane*16) so Et is unswizzled row-major; masks preloaded to registers
// before any DMA; OOB rows clamped to 999 (masked to -2e9 -> p=0).
// R9 established: zero-barrier phase C alone isn't enough — the stall is
// serial per-tile load latency, which this prefetch hides.
//
// Math:
//   qkp[h,c]  = 0.25 * sum_e W_node[c, h*16+e] * q[h*16+e]
//   compat[h,n] = sum_c E[n,c] * qkp[h,c]            (masked -> -2e9)
//   Ebar[h,c] = sum_n softmax_n(compat)[h,n] * E[n,c] (split online softmax)
//   heads -> glimpse -> gp[c] = (1/sqrt(128)) sum_d W_node[c,256+d]*glimpse[d]
//   logits[n] = sum_c E[n,c] * gp[c]; z=10*tanh; mask; log_softmax.

#define NEG (-1e9f)

__device__ __forceinline__ float rfl(float x) {
    return __int_as_float(__builtin_amdgcn_readfirstlane(__float_as_int(x)));
}

__device__ __forceinline__ void gld16(const float4* g, float4* l) {
    __builtin_amdgcn_global_load_lds(
        (const __attribute__((address_space(1))) void*)g,
        (__attribute__((address_space(3))) void*)l, 16, 0, 0);
}

__global__ __launch_bounds__(1024) void k_fused(
    const float* __restrict__ E, const float* __restrict__ Wn,
    const float* __restrict__ Wf, const float* __restrict__ Ws,
    const float* __restrict__ Wo,
    const int* __restrict__ fi, const int* __restrict__ li,
    const int* __restrict__ maskI, const unsigned char* __restrict__ maskB,
    float* __restrict__ out)
{
    const int b = blockIdx.x;
    const int t = threadIdx.x;

    __shared__ float4 Et[8192];      // 128 KB: double-buffered tile (2x4096)
    __shared__ float4 qk4[256];      // qkp, float4-slot swizzle s^(s>>2)
    __shared__ float4 pt4[256];      // per-tile p (wave-local); z[] in phase E
    __shared__ float4 EbarF4[256];
    __shared__ float4 mu4[32], e14[32], e24[32], gp4[32];
    __shared__ float q[128], heads[128], gl[128];
    __shared__ float qred[8][128];   // k-split partials; wave-merge scratch
    __shared__ float mh[8], lh[8];
    __shared__ float red[16];
    __shared__ float stat[2];
    __shared__ int flagS;

    float* const mu = (float*)mu4;
    float* const e1 = (float*)e14;
    float* const e2 = (float*)e24;
    float* const gp = (float*)gp4;
    float* const pt = (float*)pt4;
    float* const EbarF = (float*)EbarF4;
    float* const qkf = (float*)qk4;
    float* const qrf = (float*)qred;

    const float4* E4 = (const float4*)(E + (size_t)b * 128000);

    if (t == 0) flagS = 0;
    // mask-format probe: int32 upload => every word 0/1 => upper 3 bytes zero.
    const uint4 dv = ((const uint4*)maskI)[t];           // first 16 KB
    const unsigned det = (dv.x | dv.y | dv.z | dv.w) & 0xFFFFFF00u;

    const int rr = t >> 3, qq = t & 7;    // phase C/E: 128 rows x 8 octants
    const int c4 = t & 31, sl = t >> 5;   // Ebar: 32 slices x 4 rows
    const int wv = t >> 6;                // wave index
    const int lane = t & 63;

    // ---- Phase A: graph mean (scratch := Et buf0), first/last embeddings ----
    {
        const int cm = t & 31, sm = t >> 5;
        float4 acc = make_float4(0.f, 0.f, 0.f, 0.f);
        for (int r = sm; r < 1000; r += 32) {
            const float4 v = E4[r * 32 + cm];
            acc.x += v.x; acc.y += v.y; acc.z += v.z; acc.w += v.w;
        }
        Et[t] = acc;
    }
    if (t >= 512 && t < 544) {
        e14[t - 512] = E4[fi[b] * 32 + (t - 512)];
    } else if (t >= 544 && t < 576) {
        e24[t - 544] = E4[li[b] * 32 + (t - 544)];
    }
    __syncthreads();
    if (det) atomicOr(&flagS, 1);
    if (t < 32) {
        float4 acc = Et[t];
        #pragma unroll
        for (int s = 1; s < 32; ++s) {
            const float4 v = Et[s * 32 + t];
            acc.x += v.x; acc.y += v.y; acc.z += v.z; acc.w += v.w;
        }
        const float inv = 1.0f / 1000.0f;
        mu4[t] = make_float4(acc.x * inv, acc.y * inv, acc.z * inv, acc.w * inv);
    }
    __syncthreads();

    // ---- Phase B: q = mu@Wf + e1@Ws[0:128] + e2@Ws[128:256], 8-way k-split ----
    {
        const int part = t >> 7, d = t & 127;
        float acc = 0.f;
        const int k0 = part * 48;
        for (int k = k0; k < k0 + 48; ++k) {
            const float s = (k < 128) ? mu[k] : (k < 256 ? e1[k - 128] : e2[k - 256]);
            const float w = (k < 128) ? Wf[k * 128 + d] : Ws[(k - 128) * 128 + d];
            acc += s * w;
        }
        qred[part][d] = acc;
    }
    __syncthreads();
    if (t < 128) {
        float acc = 0.f;
        #pragma unroll
        for (int p = 0; p < 8; ++p) acc += qred[p][t];
        q[t] = acc;
    }
    __syncthreads();
    // qkp[h][c] -> qk4 (LDS only), slot-swizzled s^(s>>2)
    {
        const int j = t & 127, cg = t >> 7;
        const float qj = q[j];
        for (int c0 = 0; c0 < 128; c0 += 8) {
            const int c = c0 + cg;
            float v = Wn[c * 384 + j] * qj;
            v += __shfl_down(v, 8, 16);
            v += __shfl_down(v, 4, 16);
            v += __shfl_down(v, 2, 16);
            v += __shfl_down(v, 1, 16);
            if ((j & 15) == 0) {
                const int h = j >> 4, s = c >> 2;
                qkf[h * 128 + (s ^ (s >> 2)) * 4 + (c & 3)] = v * 0.25f;
            }
        }
    }
    __syncthreads();

    const bool useB = (flagS != 0);

    // ---- Phase C: wave-local online softmax, DMA double-buffer pipeline ----
    // Preload all tile masks to registers (no global register-loads inside
    // the loop -> compiler's auto-waitcnt can't drain the DMA queue).
    float madd[8];
    #pragma unroll
    for (int tl = 0; tl < 8; ++tl) {
        const int g = tl * 128 + rr;
        bool m = (g >= 1000);
        if (!m) m = useB ? (maskB[b * 1000 + g] != 0) : (maskI[b * 1000 + g] != 0);
        madd[tl] = m ? -2e9f : 0.f;
    }

    float s_m[8], s_l[8];
    #pragma unroll
    for (int h = 0; h < 8; ++h) { s_m[h] = -3e38f; s_l[h] = 0.f; }
    float4 eacc[8];
    #pragma unroll
    for (int h = 0; h < 8; ++h) eacc[h] = make_float4(0.f, 0.f, 0.f, 0.f);

    // issue tile 0 DMA: wave wv stages its rows wv*8..wv*8+7 (4 instr, lane-contig)
    {
        const int g0 = wv * 8;
        #pragma unroll
        for (int j = 0; j < 4; ++j) {
            int eidx = g0 * 32 + j * 64 + lane;
            const int row = eidx >> 5;
            if (row > 999) eidx -= (row - 999) << 5;   // clamp (masked later)
            gld16(E4 + eidx, Et + (size_t)wv * 256 + j * 64);
        }
    }

    for (int tile = 0; tile < 8; ++tile) {
        float4* const B = Et + (tile & 1) * 4096;
        // issue next tile's DMA into the other buffer
        if (tile < 7) {
            // drain this wave's DS queue first (WAR vs in-flight LDS writes)
            asm volatile("s_waitcnt lgkmcnt(0)" ::: "memory");
            float4* const Bn = Et + ((tile + 1) & 1) * 4096;
            const int g0 = (tile + 1) * 128 + wv * 8;
            #pragma unroll
            for (int j = 0; j < 4; ++j) {
                int eidx = g0 * 32 + j * 64 + lane;
                const int row = eidx >> 5;
                if (row > 999) eidx -= (row - 999) << 5;
                gld16(E4 + eidx, Bn + (size_t)wv * 256 + j * 64);
            }
            asm volatile("s_waitcnt vmcnt(4)" ::: "memory");   // tile's 4 done
        } else {
            asm volatile("s_waitcnt vmcnt(0)" ::: "memory");
        }
        // compat from LDS (own rows), butterfly over octant bits 0..2
        float pch[8];
        #pragma unroll
        for (int h = 0; h < 8; ++h) pch[h] = 0.f;
        #pragma unroll
        for (int i = 0; i < 4; ++i) {
            const int grp = qq * 4 + i;
            const float4 ev = B[rr * 32 + grp];
            const int sg = grp ^ (grp >> 2);
            #pragma unroll
            for (int h = 0; h < 8; ++h) {
                const float4 w = qk4[h * 32 + sg];
                pch[h] += ev.x * w.x + ev.y * w.y + ev.z * w.z + ev.w * w.w;
            }
        }
        #pragma unroll
        for (int m = 1; m <= 4; m <<= 1) {
            #pragma unroll
            for (int h = 0; h < 8; ++h) pch[h] += __shfl_xor(pch[h], m, 64);
        }
        #pragma unroll
        for (int h = 0; h < 8; ++h) pch[h] += madd[tile];
        // wave tile-max over its 8 rows (bits 3..5), m/al update (SGPR-pinned)
        float al[8];
        #pragma unroll
        for (int h = 0; h < 8; ++h) {
            float x = pch[h];
            x = fmaxf(x, __shfl_xor(x, 8, 64));
            x = fmaxf(x, __shfl_xor(x, 16, 64));
            x = fmaxf(x, __shfl_xor(x, 32, 64));
            const float mn = rfl(fmaxf(s_m[h], x));
            al[h] = __expf(s_m[h] - mn);
            s_m[h] = mn;
        }
        // e per lane (its row); l update via row butterfly
        float e[8];
        #pragma unroll
        for (int h = 0; h < 8; ++h) {
            e[h] = __expf(pch[h] - s_m[h]);
            float x = e[h];
            x += __shfl_xor(x, 8, 64);
            x += __shfl_xor(x, 16, 64);
            x += __shfl_xor(x, 32, 64);
            s_l[h] = rfl(s_l[h] * al[h] + x);
        }
        if (qq == 0)      pt4[rr * 2]     = make_float4(e[0], e[1], e[2], e[3]);
        else if (qq == 1) pt4[rr * 2 + 1] = make_float4(e[4], e[5], e[6], e[7]);
        asm volatile("s_waitcnt lgkmcnt(0)" ::: "memory");
        // Ebar accumulate: rows sl*4+j are within this wave's 8 rows
        #pragma unroll
        for (int h = 0; h < 8; ++h) {
            eacc[h].x *= al[h]; eacc[h].y *= al[h];
            eacc[h].z *= al[h]; eacc[h].w *= al[h];
        }
        #pragma unroll
        for (int j = 0; j < 4; ++j) {
            const int r = sl * 4 + j;
            const float4 ev = B[r * 32 + c4];
            const float4 p0 = pt4[r * 2];
            const float4 p1 = pt4[r * 2 + 1];
            eacc[0].x += p0.x * ev.x; eacc[0].y += p0.x * ev.y; eacc[0].z += p0.x * ev.z; eacc[0].w += p0.x * ev.w;
            eacc[1].x += p0.y * ev.x; eacc[1].y += p0.y * ev.y; eacc[1].z += p0.y * ev.z; eacc[1].w += p0.y * ev.w;
            eacc[2].x += p0.z * ev.x; eacc[2].y += p0.z * ev.y; eacc[2].z += p0.z * ev.z; eacc[2].w += p0.z * ev.w;
            eacc[3].x += p0.w * ev.x; eacc[3].y += p0.w * ev.y; eacc[3].z += p0.w * ev.z; eacc[3].w += p0.w * ev.w;
            eacc[4].x += p1.x * ev.x; eacc[4].y += p1.x * ev.y; eacc[4].z += p1.x * ev.z; eacc[4].w += p1.x * ev.w;
            eacc[5].x += p1.y * ev.x; eacc[5].y += p1.y * ev.y; eacc[5].z += p1.y * ev.z; eacc[5].w += p1.y * ev.w;
            eacc[6].x += p1.z * ev.x; eacc[6].y += p1.z * ev.y; eacc[6].z += p1.z * ev.z; eacc[6].w += p1.z * ev.w;
            eacc[7].x += p1.w * ev.x; eacc[7].y += p1.w * ev.y; eacc[7].z += p1.w * ev.z; eacc[7].w += p1.w * ev.w;
        }
        asm volatile("" ::: "memory");
    }

    // ---- merge 16 waves' (m,l): global m, factors f_w, global l ----
    if ((t & 63) == 0) {
        #pragma unroll
        for (int h = 0; h < 8; ++h) {
            qrf[wv * 32 + h] = s_m[h];
            qrf[wv * 32 + 8 + h] = s_l[h];
        }
    }
    __syncthreads();
    if (t < 8) {
        float m = qrf[t];
        for (int w2 = 1; w2 < 16; ++w2) m = fmaxf(m, qrf[w2 * 32 + t]);
        mh[t] = m;
    }
    __syncthreads();
    if (t < 128) {
        const int w2 = t >> 3, h = t & 7;
        const float f = __expf(qrf[w2 * 32 + h] - mh[h]);
        qrf[w2 * 32 + 16 + h] = f;
        qrf[w2 * 32 + 24 + h] = qrf[w2 * 32 + 8 + h] * f;
    }
    __syncthreads();
    if (t < 8) {
        float s = 0.f;
        for (int w2 = 0; w2 < 16; ++w2) s += qrf[w2 * 32 + 24 + t];
        lh[t] = s;
    }
    {   // rescale this wave's accumulator into the global frame
        float fw[8];
        #pragma unroll
        for (int h = 0; h < 8; ++h) fw[h] = qrf[wv * 32 + 16 + h];
        #pragma unroll
        for (int h = 0; h < 8; ++h) {
            eacc[h].x *= fw[h]; eacc[h].y *= fw[h];
            eacc[h].z *= fw[h]; eacc[h].w *= fw[h];
        }
    }
    __syncthreads();

    // ---- reduce 32 slice-partials in two stages (Et buf0 as scratch) ----
    if (sl >= 16) {
        #pragma unroll
        for (int h = 0; h < 8; ++h) Et[(sl - 16) * 256 + h * 32 + c4] = eacc[h];
    }
    __syncthreads();
    if (sl < 16) {
        #pragma unroll
        for (int h = 0; h < 8; ++h) {
            const float4 o = Et[sl * 256 + h * 32 + c4];
            eacc[h].x += o.x; eacc[h].y += o.y; eacc[h].z += o.z; eacc[h].w += o.w;
            Et[sl * 256 + h * 32 + c4] = eacc[h];
        }
    }
    __syncthreads();
    if (t < 256) {
        const int h = t >> 5, cc = t & 31;
        float4 s = make_float4(0.f, 0.f, 0.f, 0.f);
        #pragma unroll
        for (int s2 = 0; s2 < 16; ++s2) {
            const float4 v = Et[s2 * 256 + h * 32 + cc];
            s.x += v.x; s.y += v.y; s.z += v.z; s.w += v.w;
        }
        const float invl = 1.0f / lh[h];
        EbarF4[h * 32 + cc] = make_float4(s.x * invl, s.y * invl, s.z * invl, s.w * invl);
    }
    __syncthreads();

    // ---- Phase D: heads -> glimpse -> gp, 8-way k-split each ----
    {
        const int part = t >> 7, d = t & 127, h = d >> 4;
        float acc = 0.f;
        const int c0 = part * 16;
        for (int c = c0; c < c0 + 16; ++c) acc += EbarF[h * 128 + c] * Wn[c * 384 + 128 + d];
        qred[part][d] = acc;
    }
    __syncthreads();
    if (t < 128) {
        float acc = 0.f;
        #pragma unroll
        for (int p = 0; p < 8; ++p) acc += qred[p][t];
        heads[t] = acc;
    }
    __syncthreads();
    {
        const int part = t >> 7, d = t & 127;
        float acc = 0.f;
        const int j0 = part * 16;
        for (int j = j0; j < j0 + 16; ++j) acc += heads[j] * Wo[j * 128 + d];
        qred[part][d] = acc;
    }
    __syncthreads();
    if (t < 128) {
        float acc = 0.f;
        #pragma unroll
        for (int p = 0; p < 8; ++p) acc += qred[p][t];
        gl[t] = acc;
    }
    __syncthreads();
    {
        const int part = t >> 7, c = t & 127;
        float acc = 0.f;
        const int d0 = part * 16;
        for (int d = d0; d < d0 + 16; ++d) acc += Wn[c * 384 + 256 + d] * gl[d];
        qred[part][c] = acc;
    }
    __syncthreads();
    if (t < 128) {
        float acc = 0.f;
        #pragma unroll
        for (int p = 0; p < 8; ++p) acc += qred[p][t];
        gp[t] = acc * 0.08838834764831845f;   // 1/sqrt(128)
    }
    __syncthreads();

    // ---- Phase E: logits via shfl butterfly — no barriers in tile loop ----
    for (int tile = 0; tile < 8; ++tile) {
        const int g = tile * 128 + rr;
        float acc = 0.f;
        if (g < 1000) {
            #pragma unroll
            for (int i = 0; i < 4; ++i) {
                const float4 v = E4[g * 32 + qq * 4 + i];
                const float4 w = gp4[qq * 4 + i];
                acc += v.x * w.x + v.y * w.y + v.z * w.z + v.w * w.w;
            }
        }
        acc += __shfl_xor(acc, 1, 64);
        acc += __shfl_xor(acc, 2, 64);
        acc += __shfl_xor(acc, 4, 64);
        if (qq == 0 && g < 1000) {
            float zz = 10.0f * tanhf(acc);
            const bool m = useB ? (maskB[b * 1000 + g] != 0)
                                : (maskI[b * 1000 + g] != 0);
            if (m) zz = NEG;
            pt[g] = zz;
        }
    }
    __syncthreads();
    float v = (t < 1000) ? pt[t] : -3e38f;
    #pragma unroll
    for (int off = 32; off > 0; off >>= 1) v = fmaxf(v, __shfl_down(v, off, 64));
    if ((t & 63) == 0) red[t >> 6] = v;
    __syncthreads();
    if (t == 0) {
        float m = red[0];
        for (int i = 1; i < 16; ++i) m = fmaxf(m, red[i]);
        stat[0] = m;
    }
    __syncthreads();
    float sv = (t < 1000) ? __expf(pt[t] - stat[0]) : 0.f;
    #pragma unroll
    for (int off = 32; off > 0; off >>= 1) sv += __shfl_down(sv, off, 64);
    if ((t & 63) == 0) red[t >> 6] = sv;
    __syncthreads();
    if (t == 0) {
        float s = 0.f;
        for (int i = 0; i < 16; ++i) s += red[i];
        stat[1] = stat[0] + __logf(s);
    }
    __syncthreads();
    if (t < 1000)
        out[(size_t)b * 1000 + t] = pt[t] - stat[1];
}

// ---------------------------------------------------------------------------
extern "C" void kernel_launch(void* const* d_in, const int* in_sizes, int n_in,
                              void* d_out, int out_size, void* d_ws, size_t ws_size,
                              hipStream_t stream) {
    const float* E  = (const float*)d_in[0];
    const float* Wn = (const float*)d_in[1];
    const float* Wf = (const float*)d_in[2];
    const float* Ws = (const float*)d_in[3];
    const float* Wo = (const float*)d_in[4];
    const int*   fi = (const int*)d_in[5];
    const int*   li = (const int*)d_in[6];
    const int*   maskI = (const int*)d_in[7];
    const unsigned char* maskB = (const unsigned char*)d_in[7];
    float* out = (float*)d_out;

    k_fused<<<256, 1024, 0, stream>>>(E, Wn, Wf, Ws, Wo, fi, li, maskI, maskB, out);
}